// Round 6
// baseline (236.106 us; speedup 1.0000x reference)
//
#include <hip/hip_runtime.h>

// TenHotEncodeLayer: out[n, x[n,j]] = 1.0, rest zeros.
// B=8192 rows, NUM_TOKENS=32000 cols (f32), K=10 indices/row.
//
// R6: fill-clone regime. fillBufferAligned hits 6.87 TB/s at 11% occupancy
// => ~1 block/CU streaming a huge contiguous range. Previous variants all had
// 2048 resident blocks = 2048 interleaved HBM write streams (~5.2 TB/s).
// Here: 256 blocks (1/CU), each streams 32 consecutive rows = 4 MB
// sequentially. Row r+1's indices are prefetched before streaming row r
// (latency hidden under ~31 store iterations).

#define NUM_TOKENS 32000
#define KHOT 10
#define F4_PER_ROW (NUM_TOKENS / 4)   // 8000 float4 per row (128,000 B)
#define BLOCK 256
#define GRID 256                      // 1 block per CU
#define ROWS_PER_BLOCK 32             // 8192 / 256

typedef float f32x4 __attribute__((ext_vector_type(4)));

__global__ __launch_bounds__(BLOCK) void TenHotEncodeLayer_53566832115799_kernel(
    const int* __restrict__ x, float* __restrict__ out, int B) {
    const int row0 = blockIdx.x * ROWS_PER_BLOCK;

    // Prefetch row0's indices (wave-uniform -> scalar loads).
    int raw[KHOT];
    #pragma unroll
    for (int j = 0; j < KHOT; ++j) {
        const int rr = (row0 < B) ? row0 : 0;
        raw[j] = x[rr * KHOT + j];
    }

    for (int r = 0; r < ROWS_PER_BLOCK; ++r) {
        const int row = row0 + r;
        if (row >= B) break;

        // Decode current row's indices from the prefetched values.
        int      c[KHOT];    // owning float4-chunk (-1 = dropped)
        unsigned bit[KHOT];  // element bit within chunk
        #pragma unroll
        for (int j = 0; j < KHOT; ++j) {
            const int idx = raw[j];
            const bool ok = (idx >= 0) && (idx < NUM_TOKENS);
            c[j]   = ok ? (idx >> 2) : -1;
            bit[j] = 1u << (idx & 3);
        }

        // Issue next row's index loads NOW; waitcnt lands after the stream
        // loop below (~31 iterations of latency cover).
        int nxt[KHOT];
        {
            const int rn = (row + 1 < B) ? (row + 1) : row;  // clamped, always valid
            #pragma unroll
            for (int j = 0; j < KHOT; ++j) nxt[j] = x[rn * KHOT + j];
        }

        f32x4* __restrict__ rowp =
            reinterpret_cast<f32x4*>(out) + (size_t)row * F4_PER_ROW;
        for (int i = threadIdx.x; i < F4_PER_ROW; i += BLOCK) {
            unsigned m = 0u;
            #pragma unroll
            for (int j = 0; j < KHOT; ++j) {
                m |= (c[j] == i) ? bit[j] : 0u;  // dup indices OR same bit
            }
            f32x4 v;
            v.x = (m & 1u) ? 1.0f : 0.0f;
            v.y = (m & 2u) ? 1.0f : 0.0f;
            v.z = (m & 4u) ? 1.0f : 0.0f;
            v.w = (m & 8u) ? 1.0f : 0.0f;
            __builtin_nontemporal_store(v, &rowp[i]);  // streaming 16B store
        }

        #pragma unroll
        for (int j = 0; j < KHOT; ++j) raw[j] = nxt[j];
    }
}

extern "C" void kernel_launch(void* const* d_in, const int* in_sizes, int n_in,
                              void* d_out, int out_size, void* d_ws, size_t ws_size,
                              hipStream_t stream) {
    const int* x = (const int*)d_in[0];
    float* out = (float*)d_out;
    const int B = in_sizes[0] / KHOT;  // 8192
    TenHotEncodeLayer_53566832115799_kernel<<<GRID, BLOCK, 0, stream>>>(x, out, B);
}

// Round 7
// 189.521 us; speedup vs baseline: 1.2458x; 1.2458x over previous
//
#include <hip/hip_runtime.h>

// TenHotEncodeLayer: out[n, x[n,j]] = 1.0, rest zeros.
// B=8192 rows, NUM_TOKENS=32000 cols (f32), K=10 indices/row.
//
// R7: two-pass, fill-clone access pattern.
// Pass 1: GRID-STRIDE zero fill (256 blocks x 256 thr, stride = 1 MB).
//   At any instant the grid writes one contiguous 1MB window sweeping the
//   buffer linearly -> each HBM channel sees a sequential stream (rocclr
//   fillBufferAligned's regime, measured 6.87 TB/s on this chip). All
//   chunk-per-block variants presented 256-2048 separate streams -> 5.2 TB/s.
// Pass 2: scatter 81,920 ones (tiny, latency-parallel). Stream ordering
//   guarantees pass-1 visibility.

#define NUM_TOKENS 32000
#define KHOT 10
#define BLOCK 256
#define FILL_GRID 256                       // 65536 threads, like rocclr fill
#define TOTAL_F4 65536000                   // 8192*32000*4B / 16B
#define FILL_ITERS (TOTAL_F4 / (FILL_GRID * BLOCK))  // exactly 1000

typedef float f32x4 __attribute__((ext_vector_type(4)));

__global__ __launch_bounds__(BLOCK) void tenhot_fill0(f32x4* __restrict__ out) {
    size_t i = (size_t)blockIdx.x * BLOCK + threadIdx.x;
    const f32x4 z = {0.f, 0.f, 0.f, 0.f};
    #pragma unroll 1
    for (int k = 0; k < FILL_ITERS; ++k) {
        out[i] = z;              // plain store; grid sweeps linearly, 1MB/step
        i += (size_t)FILL_GRID * BLOCK;
    }
}

__global__ __launch_bounds__(BLOCK) void tenhot_scatter(
    const int* __restrict__ x, float* __restrict__ out, int total) {
    const int t = blockIdx.x * BLOCK + threadIdx.x;   // one thread per (row, j)
    if (t < total) {
        const int idx = x[t];
        const int row = t / KHOT;
        if (idx >= 0 && idx < NUM_TOKENS) {
            out[(size_t)row * NUM_TOKENS + idx] = 1.0f;  // set; dups benign
        }
    }
}

extern "C" void kernel_launch(void* const* d_in, const int* in_sizes, int n_in,
                              void* d_out, int out_size, void* d_ws, size_t ws_size,
                              hipStream_t stream) {
    const int* x = (const int*)d_in[0];
    float* out = (float*)d_out;
    const int total = in_sizes[0];               // 81920 = B*K
    tenhot_fill0<<<FILL_GRID, BLOCK, 0, stream>>>((f32x4*)out);
    tenhot_scatter<<<(total + BLOCK - 1) / BLOCK, BLOCK, 0, stream>>>(x, out, total);
}